// Round 6
// baseline (407.129 us; speedup 1.0000x reference)
//
#include <hip/hip_runtime.h>
#include <math.h>

// DIEN bf16-MFMA v4: 8-row recurrence blocks (grid=512, 2 blocks/CU),
// hs in [t][row][col] layout, ats LDS-staged in AUGRU.
// ws layout (bytes):
//  hs_bf16    52,428,800 @ 0             [50][4096][128] bf16
//  ats_f32       819,200 @ 52,428,800
//  hf_f32      2,097,152 @ 53,248,000
//  nterm_f32   2,097,152 @ 55,345,152
//  Wg          98,304 @ 57,442,304   [384][128] bf16
//  Ug          98,304 @ 57,540,608
//  Wau         98,304 @ 57,638,912
//  Uau         98,304 @ 57,737,216
//  WA          65,536 @ 57,835,520   [128][256] bf16 (k<128: W1a-W1b, k>=128: W1d)
//  WN          32,768 @ 57,901,056   [128][128] bf16 (W1b+W1c)
//  AW2         16,384 @ 57,933,824   [64][128] bf16
//  DW1        131,072 @ 57,950,208   [256][256] bf16
//  DW2         65,536 @ 58,081,280   [128][256] bf16
//  bp           1,536 @ 58,146,816   [384] f32

#define LK 0.0003f

typedef __attribute__((ext_vector_type(8))) short short8;
typedef __attribute__((ext_vector_type(4))) float f32x4;

union U8 { short8 s; unsigned short u[8]; };

__device__ __forceinline__ float sigf(float x) { return 1.0f / (1.0f + __expf(-x)); }
__device__ __forceinline__ float tanhfast(float x) { return 2.0f / (1.0f + __expf(-2.0f * x)) - 1.0f; }
__device__ __forceinline__ float lky(float v) { return v >= 0.0f ? v : LK * v; }
__device__ __forceinline__ unsigned short f2bf(float f) {
    unsigned u = __float_as_uint(f);
    return (unsigned short)((u + 0x7FFFu + ((u >> 16) & 1u)) >> 16);
}
__device__ __forceinline__ float bf2f(unsigned short h) {
    return __uint_as_float(((unsigned)h) << 16);
}
// XOR swizzle: 16B-slot permute within 8-row stripes -> <=2-way bank aliasing (free)
__device__ __forceinline__ int swz(int row, int kbyte, int stride) {
    return row * stride + (kbyte ^ ((row & 7) << 4));
}
__device__ __forceinline__ f32x4 mfma16(short8 a, short8 b, f32x4 c) {
    return __builtin_amdgcn_mfma_f32_16x16x32_bf16(a, b, c, 0, 0, 0);
}

// ---------------- pack & transpose all weights to bf16 [n][k] panels ----------------
__global__ void pack_all(
    const float* __restrict__ gW, const float* __restrict__ gU,
    const float* __restrict__ aWu, const float* __restrict__ aWr, const float* __restrict__ aWc,
    const float* __restrict__ aUu, const float* __restrict__ aUr, const float* __restrict__ aUc,
    const float* __restrict__ tW1, const float* __restrict__ tW2,
    const float* __restrict__ dW1, const float* __restrict__ dW2,
    const float* __restrict__ abu, const float* __restrict__ abr, const float* __restrict__ abc,
    unsigned short* __restrict__ Wg, unsigned short* __restrict__ Ug,
    unsigned short* __restrict__ Wau, unsigned short* __restrict__ Uau,
    unsigned short* __restrict__ WA, unsigned short* __restrict__ WN,
    unsigned short* __restrict__ AW2,
    unsigned short* __restrict__ DW1, unsigned short* __restrict__ DW2,
    float* __restrict__ bp)
{
    int i = blockIdx.x * 256 + threadIdx.x;
    if (i < 49152) {                                  // Wg/Ug: [n<384][k<128]
        int n = i >> 7, k = i & 127;
        Wg[i] = f2bf(gW[k * 384 + n]);
        Ug[i] = f2bf(gU[k * 384 + n]);
    } else if (i < 98304) {                           // Wau/Uau
        int j = i - 49152; int n = j >> 7, k = j & 127;
        int g = n >> 7, c = n & 127;
        const float* s = (g == 0) ? aWu : (g == 1) ? aWr : aWc;
        const float* u = (g == 0) ? aUu : (g == 1) ? aUr : aUc;
        Wau[j] = f2bf(s[k * 128 + c]);
        Uau[j] = f2bf(u[k * 128 + c]);
    } else if (i < 131072) {                          // WA: [n<128][k<256]
        int j = i - 98304; int n = j >> 8, k = j & 255;
        float v = (k < 128) ? (tW1[k * 128 + n] - tW1[(128 + k) * 128 + n])
                            : tW1[(384 + (k - 128)) * 128 + n];
        WA[j] = f2bf(v);
    } else if (i < 147456) {                          // WN: [n<128][k<128]
        int j = i - 131072; int n = j >> 7, k = j & 127;
        WN[j] = f2bf(tW1[(128 + k) * 128 + n] + tW1[(256 + k) * 128 + n]);
    } else if (i < 155648) {                          // AW2: [n<64][k<128]
        int j = i - 147456; int n = j >> 7, k = j & 127;
        AW2[j] = f2bf(tW2[k * 64 + n]);
    } else if (i < 221184) {                          // DW1: [n<256][k<256]
        int j = i - 155648; int n = j >> 8, k = j & 255;
        DW1[j] = f2bf(dW1[k * 256 + n]);
    } else if (i < 253952) {                          // DW2: [n<128][k<256]
        int j = i - 221184; int n = j >> 8, k = j & 255;
        DW2[j] = f2bf(dW2[k * 128 + n]);
    } else if (i < 254336) {
        int j = i - 253952;
        bp[j] = (j < 128) ? abu[j] : (j < 256) ? abr[j - 128] : abc[j - 256];
    }
}

// ---------------- nterm = news @ WN + b1  (4096 x 128, K=128) ----------------
__global__ __launch_bounds__(512, 2) void nterm_kernel(
    const float* __restrict__ inputs, const unsigned short* __restrict__ WN,
    const float* __restrict__ b1, float* __restrict__ nterm)
{
    __shared__ __align__(16) unsigned char nb[64 * 256];  // [64][128] bf16 swz

    const int tid = threadIdx.x;
    const int wv = tid >> 6, l = tid & 63, l15 = l & 15, lg = l >> 4;
    const size_t b0 = (size_t)blockIdx.x * 64;

    {
        int r = tid >> 3, c = tid & 7;
        const float* src = inputs + ((b0 + r) * 51 + 50) * 128 + c * 16;
        float4 v0 = *(const float4*)(src);
        float4 v1 = *(const float4*)(src + 4);
        float4 v2 = *(const float4*)(src + 8);
        float4 v3 = *(const float4*)(src + 12);
        U8 t0, t1;
        t0.u[0] = f2bf(v0.x); t0.u[1] = f2bf(v0.y); t0.u[2] = f2bf(v0.z); t0.u[3] = f2bf(v0.w);
        t0.u[4] = f2bf(v1.x); t0.u[5] = f2bf(v1.y); t0.u[6] = f2bf(v1.z); t0.u[7] = f2bf(v1.w);
        t1.u[0] = f2bf(v2.x); t1.u[1] = f2bf(v2.y); t1.u[2] = f2bf(v2.z); t1.u[3] = f2bf(v2.w);
        t1.u[4] = f2bf(v3.x); t1.u[5] = f2bf(v3.y); t1.u[6] = f2bf(v3.z); t1.u[7] = f2bf(v3.w);
        *(short8*)(nb + swz(r, c * 32, 256))      = t0.s;
        *(short8*)(nb + swz(r, c * 32 + 16, 256)) = t1.s;
    }
    __syncthreads();

    short8 wf[4];
#pragma unroll
    for (int kt = 0; kt < 4; ++kt)
        wf[kt] = *(const short8*)(WN + (wv * 16 + l15) * 128 + kt * 32 + lg * 8);

    f32x4 acc[4];
#pragma unroll
    for (int rt = 0; rt < 4; ++rt) acc[rt] = (f32x4){0.f, 0.f, 0.f, 0.f};
#pragma unroll
    for (int rt = 0; rt < 4; ++rt)
#pragma unroll
        for (int kt = 0; kt < 4; ++kt) {
            short8 axx = *(const short8*)(nb + swz(rt * 16 + l15, kt * 64 + lg * 16, 256));
            acc[rt] = mfma16(axx, wf[kt], acc[rt]);
        }
    float bb = b1[wv * 16 + l15];
#pragma unroll
    for (int rt = 0; rt < 4; ++rt)
#pragma unroll
        for (int j = 0; j < 4; ++j)
            nterm[(b0 + rt * 16 + lg * 4 + j) * 128 + wv * 16 + l15] = acc[rt][j] + bb;
}

// ---------------- GRU + attention fused persistent recurrence ----------------
// 8 batch rows/block, 512 threads = 8 waves, grid 512 (2 blocks/CU).
// Pipeline: step t computes h_t; L1(t-1); L2(t-2); dot->ats(t-3). 3 drain iters.
__global__ __launch_bounds__(512, 2) void gru_attn(
    const float* __restrict__ inputs, const unsigned short* __restrict__ Wt,
    const unsigned short* __restrict__ Ut, const float* __restrict__ gb,
    const unsigned short* __restrict__ WA, const unsigned short* __restrict__ AW2,
    const float* __restrict__ ab2, const float* __restrict__ nterm,
    const float* __restrict__ W3, const float* __restrict__ b3,
    unsigned short* __restrict__ hs, float* __restrict__ ats)
{
    __shared__ __align__(16) unsigned char xbuf[2][2048];   // x_t bf16 [8][128] swz
    __shared__ __align__(16) unsigned char hbuf[2][2048];   // h   bf16 [8][128] swz
    __shared__ __align__(16) unsigned char pbuf[2][2048];   // h*news bf16 swz
    __shared__ __align__(16) unsigned char a1buf[2][2048];  // a1 bf16 [8][128] swz
    __shared__ float a2buf[2][8 * 64];
    __shared__ float w3l[64];

    const int tid = threadIdx.x;
    const int wv = tid >> 6, l = tid & 63, l15 = l & 15, lg = l >> 4;
    const size_t row0 = (size_t)blockIdx.x * 8;
    const int ucol = wv * 16 + l15;            // GRU out col AND attn L1 col
    const bool rowok = (lg < 2);               // valid output rows 0..7

    // --- persistent weight fragments ---
    short8 wf[3][4], uf[3][4];
#pragma unroll
    for (int g = 0; g < 3; ++g)
#pragma unroll
        for (int kt = 0; kt < 4; ++kt) {
            int n = g * 128 + ucol;
            int k0 = kt * 32 + lg * 8;
            wf[g][kt] = *(const short8*)(Wt + n * 128 + k0);
            uf[g][kt] = *(const short8*)(Ut + n * 128 + k0);
        }
    short8 waf[8];
#pragma unroll
    for (int kt = 0; kt < 8; ++kt)
        waf[kt] = *(const short8*)(WA + ucol * 256 + kt * 32 + lg * 8);
    short8 w2f[4];
    const int n2 = (wv & 3) * 16 + l15;
    if (wv < 4) {
#pragma unroll
        for (int kt = 0; kt < 4; ++kt)
            w2f[kt] = *(const short8*)(AW2 + n2 * 128 + kt * 32 + lg * 8);
    }
    const float b2v = (wv < 4) ? ab2[n2] : 0.f;
    const float b3v = b3[0];
    if (tid < 64) w3l[tid] = W3[tid];

    const float bx0 = gb[ucol],       bx1 = gb[128 + ucol], bx2 = gb[256 + ucol];
    const float bh0 = gb[384 + ucol], bh1 = gb[512 + ucol], bh2 = gb[640 + ucol];

    float nt4[4] = {0,0,0,0}, news4[4] = {0,0,0,0};
    size_t hsbase[4] = {0,0,0,0};
    if (rowok) {
#pragma unroll
        for (int j = 0; j < 4; ++j) {
            int m = lg * 4 + j;
            nt4[j]   = nterm[(row0 + m) * 128 + ucol];
            news4[j] = inputs[((row0 + m) * 51 + 50) * 128 + ucol];
            hsbase[j] = (row0 + m) * 128 + ucol;
        }
    }

    const int sr = tid >> 5, ss = tid & 31;    // x staging: row 0..15 (valid<8), chunk
    const bool stok = (sr < 8);

    if (tid < 256) {
        *(uint2*)(hbuf[0] + tid * 8) = make_uint2(0u, 0u);
        *(uint2*)(hbuf[1] + tid * 8) = make_uint2(0u, 0u);
        *(uint2*)(pbuf[0] + tid * 8) = make_uint2(0u, 0u);
        *(uint2*)(pbuf[1] + tid * 8) = make_uint2(0u, 0u);
        *(uint2*)(a1buf[0] + tid * 8) = make_uint2(0u, 0u);
        *(uint2*)(a1buf[1] + tid * 8) = make_uint2(0u, 0u);
        *(uint2*)(xbuf[0] + tid * 8) = make_uint2(0u, 0u);
        *(uint2*)(xbuf[1] + tid * 8) = make_uint2(0u, 0u);
    }
    __syncthreads();
    if (stok) {
        float4 v = *(const float4*)&inputs[((row0 + sr) * 51) * 128 + ss * 4];
        unsigned a = (unsigned)f2bf(v.x) | ((unsigned)f2bf(v.y) << 16);
        unsigned b = (unsigned)f2bf(v.z) | ((unsigned)f2bf(v.w) << 16);
        *(uint2*)(xbuf[0] + swz(sr, ss * 8, 256)) = make_uint2(a, b);
    }
    float hreg[4] = {0.f, 0.f, 0.f, 0.f};
    __syncthreads();

    for (int t = 0; t <= 52; ++t) {
        const int p = t & 1;

        float4 xpf;
        if (stok && t < 49)
            xpf = *(const float4*)&inputs[((row0 + sr) * 51 + (t + 1)) * 128 + ss * 4];

        short8 ah[4];
        if (t <= 50) {
#pragma unroll
            for (int kt = 0; kt < 4; ++kt)
                ah[kt] = *(const short8*)(hbuf[p] + swz(l15 & 7, kt * 64 + lg * 16, 256));
        }

        // --- GRU step t ---
        if (t < 50) {
            short8 ax[4];
#pragma unroll
            for (int kt = 0; kt < 4; ++kt)
                ax[kt] = *(const short8*)(xbuf[p] + swz(l15 & 7, kt * 64 + lg * 16, 256));
            f32x4 accx[3], acch[3];
#pragma unroll
            for (int g = 0; g < 3; ++g) {
                accx[g] = (f32x4){0.f, 0.f, 0.f, 0.f};
                acch[g] = (f32x4){0.f, 0.f, 0.f, 0.f};
            }
#pragma unroll
            for (int kt = 0; kt < 4; ++kt)
#pragma unroll
                for (int g = 0; g < 3; ++g) {
                    accx[g] = mfma16(ax[kt], wf[g][kt], accx[g]);
                    acch[g] = mfma16(ah[kt], uf[g][kt], acch[g]);
                }
            if (rowok) {
#pragma unroll
                for (int j = 0; j < 4; ++j) {
                    int m = lg * 4 + j;
                    float z  = sigf(accx[0][j] + acch[0][j] + bx0 + bh0);
                    float r  = sigf(accx[1][j] + acch[1][j] + bx1 + bh1);
                    float hc = tanhfast(accx[2][j] + bx2 + r * (acch[2][j] + bh2));
                    float hn = z * hreg[j] + (1.f - z) * hc;
                    hreg[j] = hn;
                    unsigned short hb = f2bf(hn);
                    *(unsigned short*)(hbuf[p ^ 1] + swz(m, ucol * 2, 256)) = hb;
                    *(unsigned short*)(pbuf[p ^ 1] + swz(m, ucol * 2, 256)) = f2bf(hn * news4[j]);
                    hs[hsbase[j] + (size_t)t * 524288] = hb;
                }
            }
        }

        // --- attn L1 for step t-1 : a1 = relu(h@Wa + p@Wd + nterm) ---
        if (t >= 1 && t <= 50) {
            short8 pa[4];
#pragma unroll
            for (int kt = 0; kt < 4; ++kt)
                pa[kt] = *(const short8*)(pbuf[p] + swz(l15 & 7, kt * 64 + lg * 16, 256));
            f32x4 lacc = (f32x4){0.f, 0.f, 0.f, 0.f};
#pragma unroll
            for (int kt = 0; kt < 4; ++kt) lacc = mfma16(ah[kt], waf[kt], lacc);
#pragma unroll
            for (int kt = 0; kt < 4; ++kt) lacc = mfma16(pa[kt], waf[4 + kt], lacc);
            if (rowok) {
#pragma unroll
                for (int j = 0; j < 4; ++j) {
                    float v = fmaxf(lacc[j] + nt4[j], 0.f);
                    *(unsigned short*)(a1buf[p] + swz(lg * 4 + j, ucol * 2, 256)) = f2bf(v);
                }
            }
        }

        // --- attn L2 for step t-2 : a2 = relu(a1@W2 + b2)  (waves 0-3) ---
        if (t >= 2 && t <= 51 && wv < 4) {
            f32x4 c2 = (f32x4){0.f, 0.f, 0.f, 0.f};
#pragma unroll
            for (int kt = 0; kt < 4; ++kt) {
                short8 aa = *(const short8*)(a1buf[p ^ 1] + swz(l15 & 7, kt * 64 + lg * 16, 256));
                c2 = mfma16(aa, w2f[kt], c2);
            }
            if (rowok) {
#pragma unroll
                for (int j = 0; j < 4; ++j)
                    a2buf[p][(lg * 4 + j) * 64 + n2] = fmaxf(c2[j] + b2v, 0.f);
            }
        }

        // --- dot for step t-3 : ats = sig(a2.w3 + b3) ---
        if (t >= 3 && tid < 256) {
            int rrow = tid >> 5, cc = tid & 31;
            const float* a2r = &a2buf[p ^ 1][rrow * 64];
            float s = a2r[cc] * w3l[cc] + a2r[cc + 32] * w3l[cc + 32];
            s += __shfl_xor(s, 16, 32);
            s += __shfl_xor(s, 8, 32);
            s += __shfl_xor(s, 4, 32);
            s += __shfl_xor(s, 2, 32);
            s += __shfl_xor(s, 1, 32);
            if ((tid & 31) == 0) ats[(row0 + rrow) * 50 + (t - 3)] = sigf(s + b3v);
        }

        if (stok && t < 49) {
            unsigned a = (unsigned)f2bf(xpf.x) | ((unsigned)f2bf(xpf.y) << 16);
            unsigned b = (unsigned)f2bf(xpf.z) | ((unsigned)f2bf(xpf.w) << 16);
            *(uint2*)(xbuf[p ^ 1] + swz(sr, ss * 8, 256)) = make_uint2(a, b);
        }
        __syncthreads();
    }
}

// ---------------- AUGRU: 8 rows/block, single barrier per step ----------------
__global__ __launch_bounds__(512, 2) void augru_mfma(
    const unsigned short* __restrict__ hsrc, const unsigned short* __restrict__ Wt,
    const unsigned short* __restrict__ Ut, const float* __restrict__ bp,
    const float* __restrict__ ats, float* __restrict__ hf)
{
    __shared__ __align__(16) unsigned char xbuf[2][2048];
    __shared__ __align__(16) unsigned char hbuf[2][2048];
    __shared__ float atsl[8 * 50];

    const int tid = threadIdx.x;
    const int wv = tid >> 6, l = tid & 63, l15 = l & 15, lg = l >> 4;
    const size_t row0 = (size_t)blockIdx.x * 8;
    const int ucol = wv * 16 + l15;
    const bool rowok = (lg < 2);

    short8 wf[3][4], uf[3][4];
#pragma unroll
    for (int g = 0; g < 3; ++g)
#pragma unroll
        for (int kt = 0; kt < 4; ++kt) {
            int n = g * 128 + ucol;
            int k0 = kt * 32 + lg * 8;
            wf[g][kt] = *(const short8*)(Wt + n * 128 + k0);
            uf[g][kt] = *(const short8*)(Ut + n * 128 + k0);
        }
    const float bx0 = bp[ucol], bx1 = bp[128 + ucol], bx2 = bp[256 + ucol];

    const int sr = tid >> 5, ss = tid & 31;
    const bool stok = (sr < 8);

    if (tid < 256) {
        *(uint2*)(hbuf[0] + tid * 8) = make_uint2(0u, 0u);
        *(uint2*)(hbuf[1] + tid * 8) = make_uint2(0u, 0u);
        *(uint2*)(xbuf[1] + tid * 8) = make_uint2(0u, 0u);
    }
    if (tid < 400) atsl[tid] = ats[(row0 + tid / 50) * 50 + (tid % 50)];
    __syncthreads();
    if (stok) {
        uint2 v = *(const uint2*)(hsrc + (row0 + sr) * 128 + ss * 4);
        *(uint2*)(xbuf[0] + swz(sr, ss * 8, 256)) = v;
    }
    float hreg[4] = {0.f, 0.f, 0.f, 0.f};
    __syncthreads();

    for (int t = 0; t < 50; ++t) {
        const int p = t & 1;
        uint2 xnext;
        if (stok && t < 49)
            xnext = *(const uint2*)(hsrc + ((size_t)(t + 1) * 4096 + row0 + sr) * 128 + ss * 4);

        short8 ax[4], ah[4];
#pragma unroll
        for (int kt = 0; kt < 4; ++kt) {
            int off = swz(l15 & 7, kt * 64 + lg * 16, 256);
            ax[kt] = *(const short8*)(xbuf[p] + off);
            ah[kt] = *(const short8*)(hbuf[p] + off);
        }
        f32x4 accx[3], acch[3];
#pragma unroll
        for (int g = 0; g < 3; ++g) {
            accx[g] = (f32x4){0.f, 0.f, 0.f, 0.f};
            acch[g] = (f32x4){0.f, 0.f, 0.f, 0.f};
        }
#pragma unroll
        for (int kt = 0; kt < 4; ++kt)
#pragma unroll
            for (int g = 0; g < 3; ++g) {
                accx[g] = mfma16(ax[kt], wf[g][kt], accx[g]);
                acch[g] = mfma16(ah[kt], uf[g][kt], acch[g]);
            }
        if (rowok) {
#pragma unroll
            for (int j = 0; j < 4; ++j) {
                int m = lg * 4 + j;
                float u  = sigf(accx[0][j] + bx0 + acch[0][j]);
                float r  = sigf(accx[1][j] + bx1 + acch[1][j]);
                float c  = tanhfast(accx[2][j] + bx2 + r * acch[2][j]);
                float uu = atsl[m * 50 + t] * u;
                float hn = (1.f - uu) * hreg[j] + uu * c;
                hreg[j] = hn;
                *(unsigned short*)(hbuf[p ^ 1] + swz(m, ucol * 2, 256)) = f2bf(hn);
            }
        }
        if (stok && t < 49) *(uint2*)(xbuf[p ^ 1] + swz(sr, ss * 8, 256)) = xnext;
        __syncthreads();
    }
    if (rowok) {
#pragma unroll
        for (int j = 0; j < 4; ++j)
            hf[(row0 + lg * 4 + j) * 128 + ucol] = hreg[j];
    }
}

// ---------------- final: BN + 256->256->128->1, MFMA ----------------
__global__ __launch_bounds__(256, 2) void final_mfma(
    const float* __restrict__ hfv, const float* __restrict__ inputs,
    const float* __restrict__ gam, const float* __restrict__ bet,
    const float* __restrict__ mu, const float* __restrict__ var,
    const unsigned short* __restrict__ W1t, const float* __restrict__ b1,
    const unsigned short* __restrict__ W2t, const float* __restrict__ b2,
    const float* __restrict__ fW, const float* __restrict__ fb,
    float* __restrict__ out)
{
    __shared__ __align__(16) unsigned char xnb[16 * 512];  // [16][256] bf16 swz
    __shared__ __align__(16) unsigned char d1b[16 * 512];  // [16][256] bf16 swz
    __shared__ float d2b[16 * 132];
    __shared__ float wfl[128];

    const int tid = threadIdx.x;
    const int wv = tid >> 6, l = tid & 63, l15 = l & 15, lg = l >> 4;
    const size_t r0 = (size_t)blockIdx.x * 16;

    short8 w1f[4][8];
#pragma unroll
    for (int p = 0; p < 4; ++p)
#pragma unroll
        for (int kt = 0; kt < 8; ++kt) {
            int n = wv * 64 + p * 16 + l15;
            w1f[p][kt] = *(const short8*)(W1t + n * 256 + kt * 32 + lg * 8);
        }
    short8 w2f[2][8];
#pragma unroll
    for (int p = 0; p < 2; ++p)
#pragma unroll
        for (int kt = 0; kt < 8; ++kt) {
            int n = wv * 32 + p * 16 + l15;
            w2f[p][kt] = *(const short8*)(W2t + n * 256 + kt * 32 + lg * 8);
        }
    if (tid < 128) wfl[tid] = fW[tid];

    {   // stage BN-normalized input, bf16 swz
        int r = tid >> 4, c = tid & 15, k0 = c * 16;
        float v[16];
#pragma unroll
        for (int q = 0; q < 16; ++q) {
            int k = k0 + q;
            float x = (k < 128) ? hfv[(r0 + r) * 128 + k]
                                : inputs[((r0 + r) * 51 + 50) * 128 + (k - 128)];
            float s = gam[k] * rsqrtf(var[k] + 0.001f);
            v[q] = (x - mu[k]) * s + bet[k];
        }
        U8 t0, t1;
#pragma unroll
        for (int q = 0; q < 8; ++q) { t0.u[q] = f2bf(v[q]); t1.u[q] = f2bf(v[8 + q]); }
        *(short8*)(xnb + swz(r, k0 * 2, 512))      = t0.s;
        *(short8*)(xnb + swz(r, k0 * 2 + 16, 512)) = t1.s;
    }
    __syncthreads();

    // L1: [16][256] @ [256][256], leaky
    f32x4 a1[4];
#pragma unroll
    for (int p = 0; p < 4; ++p) a1[p] = (f32x4){0.f, 0.f, 0.f, 0.f};
#pragma unroll
    for (int kt = 0; kt < 8; ++kt) {
        short8 axx = *(const short8*)(xnb + swz(l15, kt * 64 + lg * 16, 512));
#pragma unroll
        for (int p = 0; p < 4; ++p) a1[p] = mfma16(axx, w1f[p][kt], a1[p]);
    }
#pragma unroll
    for (int p = 0; p < 4; ++p) {
        float bb = b1[wv * 64 + p * 16 + l15];
#pragma unroll
        for (int j = 0; j < 4; ++j) {
            int row = lg * 4 + j, col = wv * 64 + p * 16 + l15;
            *(unsigned short*)(d1b + swz(row, col * 2, 512)) = f2bf(lky(a1[p][j] + bb));
        }
    }
    __syncthreads();

    // L2: [16][256] @ [256][128], leaky
    f32x4 a2[2];
#pragma unroll
    for (int p = 0; p < 2; ++p) a2[p] = (f32x4){0.f, 0.f, 0.f, 0.f};
#pragma unroll
    for (int kt = 0; kt < 8; ++kt) {
        short8 axx = *(const short8*)(d1b + swz(l15, kt * 64 + lg * 16, 512));
#pragma unroll
        for (int p = 0; p < 2; ++p) a2[p] = mfma16(axx, w2f[p][kt], a2[p]);
    }
#pragma unroll
    for (int p = 0; p < 2; ++p) {
        float bb = b2[wv * 32 + p * 16 + l15];
#pragma unroll
        for (int j = 0; j < 4; ++j)
            d2b[(lg * 4 + j) * 132 + wv * 32 + p * 16 + l15] = lky(a2[p][j] + bb);
    }
    __syncthreads();

    if (tid < 16) {
        float s = fb[0];
#pragma unroll 8
        for (int k = 0; k < 128; ++k) s += d2b[tid * 132 + k] * wfl[k];
        out[r0 + tid] = sigf(s);
    }
}

extern "C" void kernel_launch(void* const* d_in, const int* in_sizes, int n_in,
                              void* d_out, int out_size, void* d_ws, size_t ws_size,
                              hipStream_t stream)
{
    const float* inputs   = (const float*)d_in[0];
    const float* gru_W    = (const float*)d_in[1];
    const float* gru_U    = (const float*)d_in[2];
    const float* gru_b    = (const float*)d_in[3];
    const float* att_W1   = (const float*)d_in[4];
    const float* att_b1   = (const float*)d_in[5];
    const float* att_W2   = (const float*)d_in[6];
    const float* att_b2   = (const float*)d_in[7];
    const float* att_W3   = (const float*)d_in[8];
    const float* att_b3   = (const float*)d_in[9];
    const float* au_Wu    = (const float*)d_in[10];
    const float* au_bu    = (const float*)d_in[11];
    const float* au_Uu    = (const float*)d_in[12];
    const float* au_Wr    = (const float*)d_in[13];
    const float* au_br    = (const float*)d_in[14];
    const float* au_Ur    = (const float*)d_in[15];
    const float* au_Wc    = (const float*)d_in[16];
    const float* au_bc    = (const float*)d_in[17];
    const float* au_Uc    = (const float*)d_in[18];
    const float* bn_gamma = (const float*)d_in[19];
    const float* bn_beta  = (const float*)d_in[20];
    const float* bn_mean  = (const float*)d_in[21];
    const float* bn_var   = (const float*)d_in[22];
    const float* d_W1     = (const float*)d_in[23];
    const float* d_b1     = (const float*)d_in[24];
    const float* d_W2     = (const float*)d_in[25];
    const float* d_b2     = (const float*)d_in[26];
    const float* f_W      = (const float*)d_in[27];
    const float* f_b      = (const float*)d_in[28];

    char* w = (char*)d_ws;
    unsigned short* hs  = (unsigned short*)w;
    float* ats          = (float*)(w + 52428800);
    float* hf           = (float*)(w + 53248000);
    float* nterm        = (float*)(w + 55345152);
    unsigned short* Wg  = (unsigned short*)(w + 57442304);
    unsigned short* Ug  = (unsigned short*)(w + 57540608);
    unsigned short* Wau = (unsigned short*)(w + 57638912);
    unsigned short* Uau = (unsigned short*)(w + 57737216);
    unsigned short* WA  = (unsigned short*)(w + 57835520);
    unsigned short* WN  = (unsigned short*)(w + 57901056);
    unsigned short* AW2 = (unsigned short*)(w + 57933824);
    unsigned short* DW1 = (unsigned short*)(w + 57950208);
    unsigned short* DW2 = (unsigned short*)(w + 58081280);
    float* bp           = (float*)(w + 58146816);

    pack_all<<<994, 256, 0, stream>>>(
        gru_W, gru_U, au_Wu, au_Wr, au_Wc, au_Uu, au_Ur, au_Uc,
        att_W1, att_W2, d_W1, d_W2, au_bu, au_br, au_bc,
        Wg, Ug, Wau, Uau, WA, WN, AW2, DW1, DW2, bp);
    nterm_kernel<<<64, 512, 0, stream>>>(inputs, WN, att_b1, nterm);
    gru_attn<<<512, 512, 0, stream>>>(inputs, Wg, Ug, gru_b, WA, AW2, att_b2,
                                      nterm, att_W3, att_b3, hs, ats);
    augru_mfma<<<512, 512, 0, stream>>>(hs, Wau, Uau, bp, ats, hf);
    final_mfma<<<256, 256, 0, stream>>>(hf, inputs, bn_gamma, bn_beta, bn_mean, bn_var,
                                        DW1, d_b1, DW2, d_b2, f_W, f_b, (float*)d_out);
}

// Round 7
// 170.694 us; speedup vs baseline: 2.3851x; 2.3851x over previous
//
#include <hip/hip_runtime.h>
#include <hip/hip_bf16.h>
#include <math.h>

// DIEN bf16-MFMA v5: round-5 structure (16 rows/block, grid 256, fused GRU+attn),
// with hardware bf16 converts (v_cvt_pk path), rcp-based sigmoid/tanh, fma gate blends,
// and LDS-staged ats in AUGRU.
// ws layout (bytes):
//  hs_bf16    52,428,800 @ 0             [4096][50][128] bf16
//  ats_f32       819,200 @ 52,428,800
//  hf_f32      2,097,152 @ 53,248,000
//  nterm_f32   2,097,152 @ 55,345,152
//  Wg          98,304 @ 57,442,304   [384][128] bf16
//  Ug          98,304 @ 57,540,608
//  Wau         98,304 @ 57,638,912
//  Uau         98,304 @ 57,737,216
//  WA          65,536 @ 57,835,520   [128][256] bf16 (k<128: W1a-W1b, k>=128: W1d)
//  WN          32,768 @ 57,901,056   [128][128] bf16 (W1b+W1c)
//  AW2         16,384 @ 57,933,824   [64][128] bf16
//  DW1        131,072 @ 57,950,208   [256][256] bf16
//  DW2         65,536 @ 58,081,280   [128][256] bf16
//  bp           1,536 @ 58,146,816   [384] f32

#define LK 0.0003f

typedef __attribute__((ext_vector_type(8))) short short8;
typedef __attribute__((ext_vector_type(4))) float f32x4;

union U8 { short8 s; unsigned short u[8]; };

__device__ __forceinline__ float sigf(float x) {
    return __builtin_amdgcn_rcpf(1.0f + __expf(-x));
}
__device__ __forceinline__ float tanhfast(float x) {
    return fmaf(2.0f, __builtin_amdgcn_rcpf(1.0f + __expf(-2.0f * x)), -1.0f);
}
__device__ __forceinline__ float lky(float v) { return v >= 0.0f ? v : LK * v; }
__device__ __forceinline__ unsigned short f2bf(float f) {
    __bf16 b = (__bf16)f;
    return *reinterpret_cast<unsigned short*>(&b);
}
__device__ __forceinline__ unsigned pk2(float a, float b) {
    return (unsigned)f2bf(a) | ((unsigned)f2bf(b) << 16);
}
__device__ __forceinline__ float bf2f(unsigned short h) {
    return __uint_as_float(((unsigned)h) << 16);
}
// XOR swizzle: 16B-slot permute within 8-row stripes -> <=2-way bank aliasing (free)
__device__ __forceinline__ int swz(int row, int kbyte, int stride) {
    return row * stride + (kbyte ^ ((row & 7) << 4));
}
__device__ __forceinline__ f32x4 mfma16(short8 a, short8 b, f32x4 c) {
    return __builtin_amdgcn_mfma_f32_16x16x32_bf16(a, b, c, 0, 0, 0);
}

// ---------------- pack & transpose all weights to bf16 [n][k] panels ----------------
__global__ void pack_all(
    const float* __restrict__ gW, const float* __restrict__ gU,
    const float* __restrict__ aWu, const float* __restrict__ aWr, const float* __restrict__ aWc,
    const float* __restrict__ aUu, const float* __restrict__ aUr, const float* __restrict__ aUc,
    const float* __restrict__ tW1, const float* __restrict__ tW2,
    const float* __restrict__ dW1, const float* __restrict__ dW2,
    const float* __restrict__ abu, const float* __restrict__ abr, const float* __restrict__ abc,
    unsigned short* __restrict__ Wg, unsigned short* __restrict__ Ug,
    unsigned short* __restrict__ Wau, unsigned short* __restrict__ Uau,
    unsigned short* __restrict__ WA, unsigned short* __restrict__ WN,
    unsigned short* __restrict__ AW2,
    unsigned short* __restrict__ DW1, unsigned short* __restrict__ DW2,
    float* __restrict__ bp)
{
    int i = blockIdx.x * 256 + threadIdx.x;
    if (i < 49152) {                                  // Wg/Ug: [n<384][k<128]
        int n = i >> 7, k = i & 127;
        Wg[i] = f2bf(gW[k * 384 + n]);
        Ug[i] = f2bf(gU[k * 384 + n]);
    } else if (i < 98304) {                           // Wau/Uau
        int j = i - 49152; int n = j >> 7, k = j & 127;
        int g = n >> 7, c = n & 127;
        const float* s = (g == 0) ? aWu : (g == 1) ? aWr : aWc;
        const float* u = (g == 0) ? aUu : (g == 1) ? aUr : aUc;
        Wau[j] = f2bf(s[k * 128 + c]);
        Uau[j] = f2bf(u[k * 128 + c]);
    } else if (i < 131072) {                          // WA: [n<128][k<256]
        int j = i - 98304; int n = j >> 8, k = j & 255;
        float v = (k < 128) ? (tW1[k * 128 + n] - tW1[(128 + k) * 128 + n])
                            : tW1[(384 + (k - 128)) * 128 + n];
        WA[j] = f2bf(v);
    } else if (i < 147456) {                          // WN: [n<128][k<128]
        int j = i - 131072; int n = j >> 7, k = j & 127;
        WN[j] = f2bf(tW1[(128 + k) * 128 + n] + tW1[(256 + k) * 128 + n]);
    } else if (i < 155648) {                          // AW2: [n<64][k<128]
        int j = i - 147456; int n = j >> 7, k = j & 127;
        AW2[j] = f2bf(tW2[k * 64 + n]);
    } else if (i < 221184) {                          // DW1: [n<256][k<256]
        int j = i - 155648; int n = j >> 8, k = j & 255;
        DW1[j] = f2bf(dW1[k * 256 + n]);
    } else if (i < 253952) {                          // DW2: [n<128][k<256]
        int j = i - 221184; int n = j >> 8, k = j & 255;
        DW2[j] = f2bf(dW2[k * 128 + n]);
    } else if (i < 254336) {
        int j = i - 253952;
        bp[j] = (j < 128) ? abu[j] : (j < 256) ? abr[j - 128] : abc[j - 256];
    }
}

// ---------------- nterm = news @ WN + b1  (4096 x 128, K=128) ----------------
__global__ __launch_bounds__(512, 2) void nterm_kernel(
    const float* __restrict__ inputs, const unsigned short* __restrict__ WN,
    const float* __restrict__ b1, float* __restrict__ nterm)
{
    __shared__ __align__(16) unsigned char nb[64 * 256];  // [64][128] bf16 swz

    const int tid = threadIdx.x;
    const int wv = tid >> 6, l = tid & 63, l15 = l & 15, lg = l >> 4;
    const size_t b0 = (size_t)blockIdx.x * 64;

    {
        int r = tid >> 3, c = tid & 7;
        const float* src = inputs + ((b0 + r) * 51 + 50) * 128 + c * 16;
        float4 v0 = *(const float4*)(src);
        float4 v1 = *(const float4*)(src + 4);
        float4 v2 = *(const float4*)(src + 8);
        float4 v3 = *(const float4*)(src + 12);
        *(uint4*)(nb + swz(r, c * 32, 256)) =
            make_uint4(pk2(v0.x, v0.y), pk2(v0.z, v0.w), pk2(v1.x, v1.y), pk2(v1.z, v1.w));
        *(uint4*)(nb + swz(r, c * 32 + 16, 256)) =
            make_uint4(pk2(v2.x, v2.y), pk2(v2.z, v2.w), pk2(v3.x, v3.y), pk2(v3.z, v3.w));
    }
    __syncthreads();

    short8 wf[4];
#pragma unroll
    for (int kt = 0; kt < 4; ++kt)
        wf[kt] = *(const short8*)(WN + (wv * 16 + l15) * 128 + kt * 32 + lg * 8);

    f32x4 acc[4];
#pragma unroll
    for (int rt = 0; rt < 4; ++rt) acc[rt] = (f32x4){0.f, 0.f, 0.f, 0.f};
#pragma unroll
    for (int rt = 0; rt < 4; ++rt)
#pragma unroll
        for (int kt = 0; kt < 4; ++kt) {
            short8 axx = *(const short8*)(nb + swz(rt * 16 + l15, kt * 64 + lg * 16, 256));
            acc[rt] = mfma16(axx, wf[kt], acc[rt]);
        }
    float bb = b1[wv * 16 + l15];
#pragma unroll
    for (int rt = 0; rt < 4; ++rt)
#pragma unroll
        for (int j = 0; j < 4; ++j)
            nterm[(b0 + rt * 16 + lg * 4 + j) * 128 + wv * 16 + l15] = acc[rt][j] + bb;
}

// ---------------- GRU + attention fused persistent recurrence ----------------
// 512 threads = 8 waves, 16 batch rows/block, grid 256. One barrier per step.
// Pipeline: step t computes h_t; L1(t-1); L2(t-2); dot->ats(t-3). 3 drain iters.
__global__ __launch_bounds__(512, 2) void gru_attn(
    const float* __restrict__ inputs, const unsigned short* __restrict__ Wt,
    const unsigned short* __restrict__ Ut, const float* __restrict__ gb,
    const unsigned short* __restrict__ WA, const unsigned short* __restrict__ AW2,
    const float* __restrict__ ab2, const float* __restrict__ nterm,
    const float* __restrict__ W3, const float* __restrict__ b3,
    unsigned short* __restrict__ hs, float* __restrict__ ats)
{
    __shared__ __align__(16) unsigned char xbuf[2][4096];   // x_t bf16 [16][128] swz
    __shared__ __align__(16) unsigned char hbuf[2][4096];   // h   bf16 [16][128] swz
    __shared__ __align__(16) unsigned char pbuf[2][4096];   // h*news bf16 swz
    __shared__ __align__(16) unsigned char a1buf[2][4096];  // a1 bf16 [16][128] swz
    __shared__ float a2buf[2][16 * 64];
    __shared__ float w3l[64];

    const int tid = threadIdx.x;
    const int wv = tid >> 6, l = tid & 63, l15 = l & 15, lg = l >> 4;
    const size_t row0 = (size_t)blockIdx.x * 16;
    const int ucol = wv * 16 + l15;            // GRU out col AND attn L1 col

    // --- persistent weight fragments ---
    short8 wf[3][4], uf[3][4];
#pragma unroll
    for (int g = 0; g < 3; ++g)
#pragma unroll
        for (int kt = 0; kt < 4; ++kt) {
            int n = g * 128 + ucol;
            int k0 = kt * 32 + lg * 8;
            wf[g][kt] = *(const short8*)(Wt + n * 128 + k0);
            uf[g][kt] = *(const short8*)(Ut + n * 128 + k0);
        }
    short8 waf[8];
#pragma unroll
    for (int kt = 0; kt < 8; ++kt)
        waf[kt] = *(const short8*)(WA + ucol * 256 + kt * 32 + lg * 8);
    short8 w2f[4];
    const int n2 = (wv & 3) * 16 + l15;
    if (wv < 4) {
#pragma unroll
        for (int kt = 0; kt < 4; ++kt)
            w2f[kt] = *(const short8*)(AW2 + n2 * 128 + kt * 32 + lg * 8);
    }
    const float b2v = (wv < 4) ? ab2[n2] : 0.f;
    const float b3v = b3[0];
    if (tid < 64) w3l[tid] = W3[tid];

    const float bx2 = gb[256 + ucol], bh2 = gb[640 + ucol];
    const float bz  = gb[ucol] + gb[384 + ucol];
    const float br  = gb[128 + ucol] + gb[512 + ucol];

    float nt4[4], news4[4];
    size_t hsbase[4];
#pragma unroll
    for (int j = 0; j < 4; ++j) {
        int m = lg * 4 + j;
        nt4[j]   = nterm[(row0 + m) * 128 + ucol];
        news4[j] = inputs[((row0 + m) * 51 + 50) * 128 + ucol];
        hsbase[j] = ((row0 + m) * 50) * 128 + ucol;
    }

    const int sr = tid >> 5, ss = tid & 31;    // x staging: row, 4-elem chunk

    *(uint2*)(hbuf[0] + tid * 8) = make_uint2(0u, 0u);
    {
        float4 v = *(const float4*)&inputs[((row0 + sr) * 51) * 128 + ss * 4];
        *(uint2*)(xbuf[0] + swz(sr, ss * 8, 256)) = make_uint2(pk2(v.x, v.y), pk2(v.z, v.w));
    }
    float hreg[4] = {0.f, 0.f, 0.f, 0.f};
    __syncthreads();

    for (int t = 0; t <= 52; ++t) {
        const int p = t & 1;

        float4 xpf;
        if (t < 49) xpf = *(const float4*)&inputs[((row0 + sr) * 51 + (t + 1)) * 128 + ss * 4];

        short8 ah[4];
        if (t <= 50) {
#pragma unroll
            for (int kt = 0; kt < 4; ++kt)
                ah[kt] = *(const short8*)(hbuf[p] + swz(l15, kt * 64 + lg * 16, 256));
        }

        // --- GRU step t ---
        if (t < 50) {
            short8 ax[4];
#pragma unroll
            for (int kt = 0; kt < 4; ++kt)
                ax[kt] = *(const short8*)(xbuf[p] + swz(l15, kt * 64 + lg * 16, 256));
            f32x4 accx[3], acch[3];
#pragma unroll
            for (int g = 0; g < 3; ++g) {
                accx[g] = (f32x4){0.f, 0.f, 0.f, 0.f};
                acch[g] = (f32x4){0.f, 0.f, 0.f, 0.f};
            }
#pragma unroll
            for (int kt = 0; kt < 4; ++kt)
#pragma unroll
                for (int g = 0; g < 3; ++g) {
                    accx[g] = mfma16(ax[kt], wf[g][kt], accx[g]);
                    acch[g] = mfma16(ah[kt], uf[g][kt], acch[g]);
                }
#pragma unroll
            for (int j = 0; j < 4; ++j) {
                int m = lg * 4 + j;
                float z  = sigf(accx[0][j] + acch[0][j] + bz);
                float r  = sigf(accx[1][j] + acch[1][j] + br);
                float hc = tanhfast(accx[2][j] + bx2 + r * (acch[2][j] + bh2));
                float hn = fmaf(z, hreg[j] - hc, hc);
                hreg[j] = hn;
                unsigned short hb = f2bf(hn);
                *(unsigned short*)(hbuf[p ^ 1] + swz(m, ucol * 2, 256)) = hb;
                *(unsigned short*)(pbuf[p ^ 1] + swz(m, ucol * 2, 256)) = f2bf(hn * news4[j]);
                hs[hsbase[j] + (size_t)t * 128] = hb;
            }
        }

        // --- attn L1 for step t-1 : a1 = relu(h@Wa + p@Wd + nterm) ---
        if (t >= 1 && t <= 50) {
            short8 pa[4];
#pragma unroll
            for (int kt = 0; kt < 4; ++kt)
                pa[kt] = *(const short8*)(pbuf[p] + swz(l15, kt * 64 + lg * 16, 256));
            f32x4 lacc = (f32x4){0.f, 0.f, 0.f, 0.f};
#pragma unroll
            for (int kt = 0; kt < 4; ++kt) lacc = mfma16(ah[kt], waf[kt], lacc);
#pragma unroll
            for (int kt = 0; kt < 4; ++kt) lacc = mfma16(pa[kt], waf[4 + kt], lacc);
#pragma unroll
            for (int j = 0; j < 4; ++j) {
                float v = fmaxf(lacc[j] + nt4[j], 0.f);
                *(unsigned short*)(a1buf[p] + swz(lg * 4 + j, ucol * 2, 256)) = f2bf(v);
            }
        }

        // --- attn L2 for step t-2 : a2 = relu(a1@W2 + b2)  (waves 0-3) ---
        if (t >= 2 && t <= 51 && wv < 4) {
            f32x4 c2 = (f32x4){0.f, 0.f, 0.f, 0.f};
#pragma unroll
            for (int kt = 0; kt < 4; ++kt) {
                short8 aa = *(const short8*)(a1buf[p ^ 1] + swz(l15, kt * 64 + lg * 16, 256));
                c2 = mfma16(aa, w2f[kt], c2);
            }
#pragma unroll
            for (int j = 0; j < 4; ++j)
                a2buf[p][(lg * 4 + j) * 64 + n2] = fmaxf(c2[j] + b2v, 0.f);
        }

        // --- dot for step t-3 : ats = sig(a2.w3 + b3) ---
        if (t >= 3 && tid < 256) {
            int rrow = tid >> 5, cc = tid & 31;
            const float* a2r = &a2buf[p ^ 1][rrow * 64];
            float s = a2r[cc] * w3l[cc] + a2r[cc + 32] * w3l[cc + 32];
            s += __shfl_xor(s, 16, 32);
            s += __shfl_xor(s, 8, 32);
            s += __shfl_xor(s, 4, 32);
            s += __shfl_xor(s, 2, 32);
            s += __shfl_xor(s, 1, 32);
            if ((tid & 31) == 0) ats[(row0 + rrow) * 50 + (t - 3)] = sigf(s + b3v);
        }

        if (t < 49)
            *(uint2*)(xbuf[p ^ 1] + swz(sr, ss * 8, 256)) =
                make_uint2(pk2(xpf.x, xpf.y), pk2(xpf.z, xpf.w));
        __syncthreads();
    }
}

// ---------------- AUGRU: MFMA recurrence, single barrier per step ----------------
__global__ __launch_bounds__(512, 2) void augru_mfma(
    const unsigned short* __restrict__ hsrc, const unsigned short* __restrict__ Wt,
    const unsigned short* __restrict__ Ut, const float* __restrict__ bp,
    const float* __restrict__ ats, float* __restrict__ hf)
{
    __shared__ __align__(16) unsigned char xbuf[2][4096];
    __shared__ __align__(16) unsigned char hbuf[2][4096];
    __shared__ float atsl[16 * 50];

    const int tid = threadIdx.x;
    const int wv = tid >> 6, l = tid & 63, l15 = l & 15, lg = l >> 4;
    const size_t row0 = (size_t)blockIdx.x * 16;
    const int ucol = wv * 16 + l15;

    short8 wf[3][4], uf[3][4];
#pragma unroll
    for (int g = 0; g < 3; ++g)
#pragma unroll
        for (int kt = 0; kt < 4; ++kt) {
            int n = g * 128 + ucol;
            int k0 = kt * 32 + lg * 8;
            wf[g][kt] = *(const short8*)(Wt + n * 128 + k0);
            uf[g][kt] = *(const short8*)(Ut + n * 128 + k0);
        }
    const float bx0 = bp[ucol], bx1 = bp[128 + ucol], bx2 = bp[256 + ucol];

    const int sr = tid >> 5, ss = tid & 31;

    *(uint2*)(hbuf[0] + tid * 8) = make_uint2(0u, 0u);
    if (tid < 400) {
        atsl[tid] = ats[row0 * 50 + tid];
        atsl[tid + 400] = ats[row0 * 50 + tid + 400];
    }
    {
        uint2 v = *(const uint2*)(hsrc + ((row0 + sr) * 50) * 128 + ss * 4);
        *(uint2*)(xbuf[0] + swz(sr, ss * 8, 256)) = v;
    }
    float hreg[4] = {0.f, 0.f, 0.f, 0.f};
    __syncthreads();

    for (int t = 0; t < 50; ++t) {
        const int p = t & 1;
        uint2 xnext;
        if (t < 49) xnext = *(const uint2*)(hsrc + ((row0 + sr) * 50 + t + 1) * 128 + ss * 4);

        short8 ax[4], ah[4];
#pragma unroll
        for (int kt = 0; kt < 4; ++kt) {
            int off = swz(l15, kt * 64 + lg * 16, 256);
            ax[kt] = *(const short8*)(xbuf[p] + off);
            ah[kt] = *(const short8*)(hbuf[p] + off);
        }
        f32x4 accx[3], acch[3];
#pragma unroll
        for (int g = 0; g < 3; ++g) {
            accx[g] = (f32x4){0.f, 0.f, 0.f, 0.f};
            acch[g] = (f32x4){0.f, 0.f, 0.f, 0.f};
        }
#pragma unroll
        for (int kt = 0; kt < 4; ++kt)
#pragma unroll
            for (int g = 0; g < 3; ++g) {
                accx[g] = mfma16(ax[kt], wf[g][kt], accx[g]);
                acch[g] = mfma16(ah[kt], uf[g][kt], acch[g]);
            }
#pragma unroll
        for (int j = 0; j < 4; ++j) {
            int m = lg * 4 + j;
            float u  = sigf(accx[0][j] + bx0 + acch[0][j]);
            float r  = sigf(accx[1][j] + bx1 + acch[1][j]);
            float c  = tanhfast(accx[2][j] + bx2 + r * acch[2][j]);
            float uu = atsl[m * 50 + t] * u;
            float hn = fmaf(uu, c - hreg[j], hreg[j]);
            hreg[j] = hn;
            *(unsigned short*)(hbuf[p ^ 1] + swz(m, ucol * 2, 256)) = f2bf(hn);
        }
        if (t < 49) *(uint2*)(xbuf[p ^ 1] + swz(sr, ss * 8, 256)) = xnext;
        __syncthreads();
    }
#pragma unroll
    for (int j = 0; j < 4; ++j)
        hf[(row0 + lg * 4 + j) * 128 + ucol] = hreg[j];
}

// ---------------- final: BN + 256->256->128->1, MFMA ----------------
__global__ __launch_bounds__(256, 2) void final_mfma(
    const float* __restrict__ hfv, const float* __restrict__ inputs,
    const float* __restrict__ gam, const float* __restrict__ bet,
    const float* __restrict__ mu, const float* __restrict__ var,
    const unsigned short* __restrict__ W1t, const float* __restrict__ b1,
    const unsigned short* __restrict__ W2t, const float* __restrict__ b2,
    const float* __restrict__ fW, const float* __restrict__ fb,
    float* __restrict__ out)
{
    __shared__ __align__(16) unsigned char xnb[16 * 512];  // [16][256] bf16 swz
    __shared__ __align__(16) unsigned char d1b[16 * 512];  // [16][256] bf16 swz
    __shared__ float d2b[16 * 132];
    __shared__ float wfl[128];

    const int tid = threadIdx.x;
    const int wv = tid >> 6, l = tid & 63, l15 = l & 15, lg = l >> 4;
    const size_t r0 = (size_t)blockIdx.x * 16;

    short8 w1f[4][8];
#pragma unroll
    for (int p = 0; p < 4; ++p)
#pragma unroll
        for (int kt = 0; kt < 8; ++kt) {
            int n = wv * 64 + p * 16 + l15;
            w1f[p][kt] = *(const short8*)(W1t + n * 256 + kt * 32 + lg * 8);
        }
    short8 w2f[2][8];
#pragma unroll
    for (int p = 0; p < 2; ++p)
#pragma unroll
        for (int kt = 0; kt < 8; ++kt) {
            int n = wv * 32 + p * 16 + l15;
            w2f[p][kt] = *(const short8*)(W2t + n * 256 + kt * 32 + lg * 8);
        }
    if (tid < 128) wfl[tid] = fW[tid];

    {   // stage BN-normalized input, bf16 swz
        int r = tid >> 4, c = tid & 15, k0 = c * 16;
        float v[16];
#pragma unroll
        for (int q = 0; q < 16; ++q) {
            int k = k0 + q;
            float x = (k < 128) ? hfv[(r0 + r) * 128 + k]
                                : inputs[((r0 + r) * 51 + 50) * 128 + (k - 128)];
            float s = gam[k] * rsqrtf(var[k] + 0.001f);
            v[q] = (x - mu[k]) * s + bet[k];
        }
        *(uint4*)(xnb + swz(r, k0 * 2, 512)) =
            make_uint4(pk2(v[0], v[1]), pk2(v[2], v[3]), pk2(v[4], v[5]), pk2(v[6], v[7]));
        *(uint4*)(xnb + swz(r, k0 * 2 + 16, 512)) =
            make_uint4(pk2(v[8], v[9]), pk2(v[10], v[11]), pk2(v[12], v[13]), pk2(v[14], v[15]));
    }
    __syncthreads();

    // L1: [16][256] @ [256][256], leaky
    f32x4 a1[4];
#pragma unroll
    for (int p = 0; p < 4; ++p) a1[p] = (f32x4){0.f, 0.f, 0.f, 0.f};
#pragma unroll
    for (int kt = 0; kt < 8; ++kt) {
        short8 axx = *(const short8*)(xnb + swz(l15, kt * 64 + lg * 16, 512));
#pragma unroll
        for (int p = 0; p < 4; ++p) a1[p] = mfma16(axx, w1f[p][kt], a1[p]);
    }
#pragma unroll
    for (int p = 0; p < 4; ++p) {
        float bb = b1[wv * 64 + p * 16 + l15];
#pragma unroll
        for (int j = 0; j < 4; ++j) {
            int row = lg * 4 + j, col = wv * 64 + p * 16 + l15;
            *(unsigned short*)(d1b + swz(row, col * 2, 512)) = f2bf(lky(a1[p][j] + bb));
        }
    }
    __syncthreads();

    // L2: [16][256] @ [256][128], leaky
    f32x4 a2[2];
#pragma unroll
    for (int p = 0; p < 2; ++p) a2[p] = (f32x4){0.f, 0.f, 0.f, 0.f};
#pragma unroll
    for (int kt = 0; kt < 8; ++kt) {
        short8 axx = *(const short8*)(d1b + swz(l15, kt * 64 + lg * 16, 512));
#pragma unroll
        for (int p = 0; p < 2; ++p) a2[p] = mfma16(axx, w2f[p][kt], a2[p]);
    }
#pragma unroll
    for (int p = 0; p < 2; ++p) {
        float bb = b2[wv * 32 + p * 16 + l15];
#pragma unroll
        for (int j = 0; j < 4; ++j)
            d2b[(lg * 4 + j) * 132 + wv * 32 + p * 16 + l15] = lky(a2[p][j] + bb);
    }
    __syncthreads();

    if (tid < 16) {
        float s = fb[0];
#pragma unroll 8
        for (int k = 0; k < 128; ++k) s += d2b[tid * 132 + k] * wfl[k];
        out[r0 + tid] = sigf(s);
    }
}

extern "C" void kernel_launch(void* const* d_in, const int* in_sizes, int n_in,
                              void* d_out, int out_size, void* d_ws, size_t ws_size,
                              hipStream_t stream)
{
    const float* inputs   = (const float*)d_in[0];
    const float* gru_W    = (const float*)d_in[1];
    const float* gru_U    = (const float*)d_in[2];
    const float* gru_b    = (const float*)d_in[3];
    const float* att_W1   = (const float*)d_in[4];
    const float* att_b1   = (const float*)d_in[5];
    const float* att_W2   = (const float*)d_in[6];
    const float* att_b2   = (const float*)d_in[7];
    const float* att_W3   = (const float*)d_in[8];
    const float* att_b3   = (const float*)d_in[9];
    const float* au_Wu    = (const float*)d_in[10];
    const float* au_bu    = (const float*)d_in[11];
    const float* au_Uu    = (const float*)d_in[12];
    const float* au_Wr    = (const float*)d_in[13];
    const float* au_br    = (const float*)d_in[14];
    const float* au_Ur    = (const float*)d_in[15];
    const float* au_Wc    = (const float*)d_in[16];
    const float* au_bc    = (const float*)d_in[17];
    const float* au_Uc    = (const float*)d_in[18];
    const float* bn_gamma = (const float*)d_in[19];
    const float* bn_beta  = (const float*)d_in[20];
    const float* bn_mean  = (const float*)d_in[21];
    const float* bn_var   = (const float*)d_in[22];
    const float* d_W1     = (const float*)d_in[23];
    const float* d_b1     = (const float*)d_in[24];
    const float* d_W2     = (const float*)d_in[25];
    const float* d_b2     = (const float*)d_in[26];
    const float* f_W      = (const float*)d_in[27];
    const float* f_b      = (const float*)d_in[28];

    char* w = (char*)d_ws;
    unsigned short* hs  = (unsigned short*)w;
    float* ats          = (float*)(w + 52428800);
    float* hf           = (float*)(w + 53248000);
    float* nterm        = (float*)(w + 55345152);
    unsigned short* Wg  = (unsigned short*)(w + 57442304);
    unsigned short* Ug  = (unsigned short*)(w + 57540608);
    unsigned short* Wau = (unsigned short*)(w + 57638912);
    unsigned short* Uau = (unsigned short*)(w + 57737216);
    unsigned short* WA  = (unsigned short*)(w + 57835520);
    unsigned short* WN  = (unsigned short*)(w + 57901056);
    unsigned short* AW2 = (unsigned short*)(w + 57933824);
    unsigned short* DW1 = (unsigned short*)(w + 57950208);
    unsigned short* DW2 = (unsigned short*)(w + 58081280);
    float* bp           = (float*)(w + 58146816);

    pack_all<<<994, 256, 0, stream>>>(
        gru_W, gru_U, au_Wu, au_Wr, au_Wc, au_Uu, au_Ur, au_Uc,
        att_W1, att_W2, d_W1, d_W2, au_bu, au_br, au_bc,
        Wg, Ug, Wau, Uau, WA, WN, AW2, DW1, DW2, bp);
    nterm_kernel<<<64, 512, 0, stream>>>(inputs, WN, att_b1, nterm);
    gru_attn<<<256, 512, 0, stream>>>(inputs, Wg, Ug, gru_b, WA, AW2, att_b2,
                                      nterm, att_W3, att_b3, hs, ats);
    augru_mfma<<<256, 512, 0, stream>>>(hs, Wau, Uau, bp, ats, hf);
    final_mfma<<<256, 256, 0, stream>>>(hf, inputs, bn_gamma, bn_beta, bn_mean, bn_var,
                                        DW1, d_b1, DW2, d_b2, f_W, f_b, (float*)d_out);
}